// Round 5
// baseline (43.215 us; speedup 1.0000x reference)
//
#include <hip/hip_runtime.h>

#define BB 16384
#define CC 10
#define KK 20
#define DD 128

// fast, accurate-enough log sigmoid: logsig(x) = min(x,0) - log(1 + exp(-|x|))
__device__ __forceinline__ float lsg(float x) {
    return fminf(x, 0.0f) - __logf(1.0f + __expf(-fabsf(x)));
}

// butterfly add via ds_swizzle (xor pattern). MASK is ICE.
template <int MASK>
__device__ __forceinline__ float swz_add(float v) {
    int r = __builtin_amdgcn_ds_swizzle(__float_as_int(v), MASK);
    return v + __int_as_float(r);
}

__device__ __forceinline__ float dot4(float4 a, float4 b) {
    return a.x * b.x + a.y * b.y + a.z * b.z + a.w * b.w;
}
__device__ __forceinline__ void add4(float4& a, float4 b) {
    a.x += b.x; a.y += b.y; a.z += b.z; a.w += b.w;
}

// 16 lanes per b, 4 b per wave, 16 b per block. VGPR cap 128 (4 waves/SIMD
// is the grid residency anyway); deep explicit MLP via staged gather batches.
__global__ __launch_bounds__(256, 4) void w2v_loss_kernel(
    const int*   __restrict__ context,   // [B, C]
    const int*   __restrict__ target,    // [B]
    const int*   __restrict__ negs,      // [B, K]
    const float* __restrict__ embW,      // [V, D]
    const float* __restrict__ ctxW,      // [V, D]
    float*       __restrict__ block_part // [gridDim.x]
) {
    const int tid   = threadIdx.x;
    const int wave  = tid >> 6;
    const int lane  = tid & 63;
    const int group = lane >> 4;
    const int gl    = lane & 15;
    const int bl    = wave * 4 + group;
    const int b0    = blockIdx.x * 16;

    __shared__ int s_ctx[16 * CC];
    __shared__ int s_tgt[16];
    __shared__ int s_neg[16 * KK];
    __shared__ float sp[4];

    if (tid < 16 * CC) s_ctx[tid] = context[b0 * CC + tid];
    if (tid < 16)      s_tgt[tid] = target[b0 + tid];
    s_neg[tid] = negs[b0 * KK + tid];
    if (tid < 16 * KK - 256) s_neg[256 + tid] = negs[b0 * KK + 256 + tid];
    __syncthreads();

    const float4* ctxW4 = reinterpret_cast<const float4*>(ctxW);
    const float4* embW4 = reinterpret_cast<const float4*>(embW);

    // ---- issue target row + negative batch 0 FIRST: latency hides under ctx ----
    const int trow = s_tgt[bl] * (DD / 4);
    float4 ta = embW4[trow + gl];
    float4 tb = embW4[trow + 16 + gl];

    float4 na0[4], nb0[4], na1[4], nb1[4];

#define NPREF(A, B, BASE)                                         \
    {                                                             \
        _Pragma("unroll")                                         \
        for (int i = 0; i < 4; ++i) {                             \
            const int r = s_neg[bl * KK + (BASE) + i] * (DD / 4); \
            A[i] = ctxW4[r + gl];                                 \
            B[i] = ctxW4[r + 16 + gl];                            \
        }                                                         \
    }

    NPREF(na0, nb0, 0)

    // ---- context mean: 2 staged batches of 5 (10 loads in flight each) ----
    float4 accA, accB;
    {
        float4 ca[5], cb[5];
        #pragma unroll
        for (int c = 0; c < 5; ++c) {
            const int r = s_ctx[bl * CC + c] * (DD / 4);
            ca[c] = ctxW4[r + gl];
            cb[c] = ctxW4[r + 16 + gl];
        }
        accA = ca[0]; accB = cb[0];
        #pragma unroll
        for (int c = 1; c < 5; ++c) { add4(accA, ca[c]); add4(accB, cb[c]); }
        #pragma unroll
        for (int c = 0; c < 5; ++c) {
            const int r = s_ctx[bl * CC + 5 + c] * (DD / 4);
            ca[c] = ctxW4[r + gl];
            cb[c] = ctxW4[r + 16 + gl];
        }
        #pragma unroll
        for (int c = 0; c < 5; ++c) { add4(accA, ca[c]); add4(accB, cb[c]); }
    }
    const float inv = 1.0f / CC;
    accA.x *= inv; accA.y *= inv; accA.z *= inv; accA.w *= inv;
    accB.x *= inv; accB.y *= inv; accB.z *= inv; accB.w *= inv;

    float pd = dot4(accA, ta) + dot4(accB, tb);

    // ---- negatives: double-buffered batches of 4, fully static (no scratch) ----
    float nd[KK];

#define NCONS(A, B, BASE)                                         \
    {                                                             \
        _Pragma("unroll")                                         \
        for (int i = 0; i < 4; ++i)                               \
            nd[(BASE) + i] = dot4(accA, A[i]) + dot4(accB, B[i]); \
    }

    NPREF(na1, nb1, 4)
    NCONS(na0, nb0, 0)
    NPREF(na0, nb0, 8)
    NCONS(na1, nb1, 4)
    NPREF(na1, nb1, 12)
    NCONS(na0, nb0, 8)
    NPREF(na0, nb0, 16)
    NCONS(na1, nb1, 12)
    NCONS(na0, nb0, 16)

#undef NPREF
#undef NCONS

    // ---- reduce over the 16 lanes of the group: xor 1,2,4,8 via ds_swizzle ----
    pd = swz_add<0x041F>(pd);
    #pragma unroll
    for (int k = 0; k < KK; ++k) nd[k] = swz_add<0x041F>(nd[k]);
    pd = swz_add<0x081F>(pd);
    #pragma unroll
    for (int k = 0; k < KK; ++k) nd[k] = swz_add<0x081F>(nd[k]);
    pd = swz_add<0x101F>(pd);
    #pragma unroll
    for (int k = 0; k < KK; ++k) nd[k] = swz_add<0x101F>(nd[k]);
    pd = swz_add<0x201F>(pd);
    #pragma unroll
    for (int k = 0; k < KK; ++k) nd[k] = swz_add<0x201F>(nd[k]);

    // ---- per-b score ----
    float score = lsg(pd);
    #pragma unroll
    for (int k = 0; k < KK; ++k) score += lsg(-nd[k]);

    // ---- combine 4 groups: xor16 (swizzle) + xor32 (shfl) ----
    float s = swz_add<0x401F>(score);
    s += __shfl_xor(s, 32, 64);

    if (lane == 0) sp[wave] = s;
    __syncthreads();
    if (tid == 0)
        block_part[blockIdx.x] = sp[0] + sp[1] + sp[2] + sp[3];
}

__global__ __launch_bounds__(256) void w2v_finish_kernel(
    const float* __restrict__ part, float* __restrict__ out, int n, float scale)
{
    __shared__ float sm[4];
    float s = 0.f;
    for (int i = threadIdx.x; i < n; i += 256) s += part[i];
    #pragma unroll
    for (int off = 32; off; off >>= 1) s += __shfl_xor(s, off, 64);
    const int wave = threadIdx.x >> 6;
    const int lane = threadIdx.x & 63;
    if (lane == 0) sm[wave] = s;
    __syncthreads();
    if (threadIdx.x == 0) out[0] = (sm[0] + sm[1] + sm[2] + sm[3]) * scale;
}

extern "C" void kernel_launch(void* const* d_in, const int* in_sizes, int n_in,
                              void* d_out, int out_size, void* d_ws, size_t ws_size,
                              hipStream_t stream) {
    const int*   context = (const int*)d_in[0];
    const int*   target  = (const int*)d_in[1];
    const int*   negs    = (const int*)d_in[2];
    const float* embW    = (const float*)d_in[3];
    const float* ctxW    = (const float*)d_in[4];
    float* out = (float*)d_out;

    float* block_part = (float*)d_ws;          // 1024 floats = 4 KB scratch
    const int nblocks = BB / 16;               // 1024 blocks x 16 b's

    w2v_loss_kernel<<<nblocks, 256, 0, stream>>>(context, target, negs, embW, ctxW, block_part);
    w2v_finish_kernel<<<1, 256, 0, stream>>>(block_part, out, nblocks, -1.0f / (float)BB);
}